// Round 1
// baseline (179029.565 us; speedup 1.0000x reference)
//
#include <hip/hip_runtime.h>
#include <hip/hip_cooperative_groups.h>

namespace cg = cooperative_groups;

#define T_   256
#define B_   64
#define H_   1024
#define Hh_  512
#define L_   2
#define K1_  1536
#define MAXF 0.875f

__device__ __forceinline__ float sigmoidf_(float x) {
    return 1.0f / (1.0f + __expf(-x));
}

// dot over K=1536: first 1024 from x (float4-aligned), last 512 from tail.
// w = W + n (column n of a row-major K1 x N matrix).
__device__ __forceinline__ float dotK(const float4* __restrict__ x4,
                                      const float4* __restrict__ t4,
                                      const float* __restrict__ w, int N) {
    float acc = 0.0f;
#pragma unroll 8
    for (int k4 = 0; k4 < H_ / 4; ++k4) {
        float4 a = x4[k4];
        const float* wp = w + (size_t)(k4 * 4) * N;
        acc += a.x * wp[0] + a.y * wp[(size_t)N] + a.z * wp[(size_t)2 * N] + a.w * wp[(size_t)3 * N];
    }
#pragma unroll 8
    for (int k4 = 0; k4 < Hh_ / 4; ++k4) {
        float4 a = t4[k4];
        const float* wp = w + (size_t)(H_ + k4 * 4) * N;
        acc += a.x * wp[0] + a.y * wp[(size_t)N] + a.z * wp[(size_t)2 * N] + a.w * wp[(size_t)3 * N];
    }
    return acc;
}

__global__ __launch_bounds__(256, 1) void revgru_persistent(
    const int* __restrict__ seq, const float* __restrict__ h0,
    const float* __restrict__ emb,
    const float* __restrict__ Wzr1, const float* __restrict__ bzr1,
    const float* __restrict__ Wg1,  const float* __restrict__ bg1,
    const float* __restrict__ Wzr2, const float* __restrict__ bzr2,
    const float* __restrict__ Wg2,  const float* __restrict__ bg2,
    float* __restrict__ hout, float* __restrict__ zbuf, float* __restrict__ rhbuf)
{
    cg::grid_group grid = cg::this_grid();
    const int bi  = blockIdx.x;   // 0..255 — owns fixed output columns forever (L2 locality)
    const int tid = threadIdx.x;  // 0..255

    // init: h state (in d_out) <- h0
    for (int i = bi * 256 + tid; i < L_ * B_ * H_; i += 256 * 256) hout[i] = h0[i];
    grid.sync();

    const int rA = tid >> 2;          // batch row for N=1024 phases
    const int nA = bi * 4 + (tid & 3);   // column for N=1024 phases
    const int rB = tid >> 1;          // batch row for N=512 phases (tid<128)
    const int nB = bi * 2 + (tid & 1);   // column for N=512 phases

    for (int t = 0; t < T_; ++t) {
        for (int l = 0; l < L_; ++l) {
            const float* Wz1 = Wzr1 + (size_t)l * K1_ * H_;
            const float* Wg1l = Wg1 + (size_t)l * K1_ * Hh_;
            const float* Wz2 = Wzr2 + (size_t)l * K1_ * H_;
            const float* Wg2l = Wg2 + (size_t)l * K1_ * Hh_;

            // ---- Phase 1: zr1 = [x, h2] @ Wzr1 + b ----
            {
                const int row = rA, n = nA;
                const float* x = (l == 0) ? emb + (size_t)seq[t * B_ + row] * H_
                                          : hout + (size_t)row * H_;
                const float* h2 = hout + ((size_t)l * B_ + row) * H_ + Hh_;
                float acc = bzr1[l * H_ + n] +
                            dotK((const float4*)x, (const float4*)h2, Wz1 + n, H_);
                float s = sigmoidf_(acc);
                if (n < Hh_) zbuf[row * Hh_ + n] = s * MAXF + (1.0f - MAXF);
                else         rhbuf[row * Hh_ + (n - Hh_)] = s * h2[n - Hh_];
            }
            grid.sync();

            // ---- Phase 2: g1 = tanh([x, r1*h2] @ Wg1 + b); h1 <- z1*h1+(1-z1)*g1 ----
            if (tid < 128) {
                const int row = rB, n = nB;
                const float* x = (l == 0) ? emb + (size_t)seq[t * B_ + row] * H_
                                          : hout + (size_t)row * H_;
                const float* rh = rhbuf + row * Hh_;
                float acc = bg1[l * Hh_ + n] +
                            dotK((const float4*)x, (const float4*)rh, Wg1l + n, Hh_);
                float g = tanhf(acc);
                float z = zbuf[row * Hh_ + n];
                float* h1 = hout + ((size_t)l * B_ + row) * H_;
                h1[n] = z * h1[n] + (1.0f - z) * g;
            }
            grid.sync();

            // ---- Phase 3: zr2 = [x, h1n] @ Wzr2 + b ----
            {
                const int row = rA, n = nA;
                const float* x = (l == 0) ? emb + (size_t)seq[t * B_ + row] * H_
                                          : hout + (size_t)row * H_;
                const float* h1 = hout + ((size_t)l * B_ + row) * H_;
                float acc = bzr2[l * H_ + n] +
                            dotK((const float4*)x, (const float4*)h1, Wz2 + n, H_);
                float s = sigmoidf_(acc);
                if (n < Hh_) zbuf[row * Hh_ + n] = s * MAXF + (1.0f - MAXF);
                else         rhbuf[row * Hh_ + (n - Hh_)] = s * h1[n - Hh_];
            }
            grid.sync();

            // ---- Phase 4: g2 = tanh([x, r2*h1n] @ Wg2 + b); h2 <- z2*h2+(1-z2)*g2 ----
            if (tid < 128) {
                const int row = rB, n = nB;
                const float* x = (l == 0) ? emb + (size_t)seq[t * B_ + row] * H_
                                          : hout + (size_t)row * H_;
                const float* rh = rhbuf + row * Hh_;
                float acc = bg2[l * Hh_ + n] +
                            dotK((const float4*)x, (const float4*)rh, Wg2l + n, Hh_);
                float g = tanhf(acc);
                float z = zbuf[row * Hh_ + n];
                float* h2 = hout + ((size_t)l * B_ + row) * H_ + Hh_;
                h2[n] = z * h2[n] + (1.0f - z) * g;
            }
            grid.sync();
        }
    }
}

extern "C" void kernel_launch(void* const* d_in, const int* in_sizes, int n_in,
                              void* d_out, int out_size, void* d_ws, size_t ws_size,
                              hipStream_t stream) {
    (void)in_sizes; (void)n_in; (void)out_size; (void)ws_size;
    const int*   seq  = (const int*)  d_in[0];
    const float* h0   = (const float*)d_in[1];
    const float* emb  = (const float*)d_in[2];
    const float* Wzr1 = (const float*)d_in[3];
    const float* bzr1 = (const float*)d_in[4];
    const float* Wg1  = (const float*)d_in[5];
    const float* bg1  = (const float*)d_in[6];
    const float* Wzr2 = (const float*)d_in[7];
    const float* bzr2 = (const float*)d_in[8];
    const float* Wg2  = (const float*)d_in[9];
    const float* bg2  = (const float*)d_in[10];
    float* out   = (float*)d_out;
    float* zbuf  = (float*)d_ws;              // B*Hh
    float* rhbuf = zbuf + B_ * Hh_;           // B*Hh

    void* args[] = { &seq, &h0, &emb, &Wzr1, &bzr1, &Wg1, &bg1,
                     &Wzr2, &bzr2, &Wg2, &bg2, &out, &zbuf, &rhbuf };
    hipLaunchCooperativeKernel((void*)revgru_persistent, dim3(256), dim3(256),
                               args, 0, stream);
}

// Round 2
// 95281.903 us; speedup vs baseline: 1.8789x; 1.8789x over previous
//
#include <hip/hip_runtime.h>
#include <hip/hip_cooperative_groups.h>

namespace cg = cooperative_groups;

#define T_   256
#define B_   64
#define H_   1024
#define Hh_  512
#define L_   2
#define K1_  1536
#define MAXF 0.875f

// ---- ws float offsets ----
#define OFF_WZR1T 0u                        // [2][1024][1536]
#define OFF_WG1T  3145728u                  // [2][512][1536]
#define OFF_WZR2T 4718592u                  // [2][1024][1536]
#define OFF_WG2T  7864320u                  // [2][512][1536]
#define OFF_XT    9437184u                  // [1024][64]
#define OFF_HT    9502720u                  // [2][1024][64]
#define OFF_ZT    9633792u                  // [512][64]
#define OFF_RHT   9666560u                  // [512][64]
// total 9,699,328 floats = 38.8 MB of ws

// Tiled transpose: src [L][K1][N] -> dst [L][N][K1]
__global__ __launch_bounds__(256) void transpose_w(const float* __restrict__ src,
                                                   float* __restrict__ dst, int N) {
    __shared__ float tile[64][65];
    const int l = blockIdx.z;
    const int k0 = blockIdx.x * 64, n0 = blockIdx.y * 64;
    const float* s = src + (size_t)l * K1_ * N;
    float* d = dst + (size_t)l * N * K1_;
    const int tx = threadIdx.x & 63, ty = threadIdx.x >> 6;
#pragma unroll
    for (int i = 0; i < 64; i += 4)
        tile[i + ty][tx] = s[(size_t)(k0 + i + ty) * N + (n0 + tx)];
    __syncthreads();
#pragma unroll
    for (int i = 0; i < 64; i += 4)
        d[(size_t)(n0 + i + ty) * K1_ + (k0 + tx)] = tile[tx][i + ty];
}

// One GEMM phase: C[64 rows][NC cols] = A[64][1536] @ W, 8-way K-split over waves.
// A is transposed (k-major, 64 rows contiguous): lane = row -> coalesced.
// W is transposed (col-major, k contiguous): address is wave-uniform -> scalar loads.
// Returns reduced value for tid < 64*NC (r = tid&63, c = tid>>6).
template<int NC>
__device__ __forceinline__ float phase_gemm(const float* __restrict__ Axlo,
                                            const float* __restrict__ Ahi,
                                            const float* __restrict__ WTc,
                                            float* __restrict__ part) {
    const int tid  = threadIdx.x;
    const int lane = tid & 63;
    const int wu   = __builtin_amdgcn_readfirstlane(tid >> 6);  // wave id 0..7, uniform
    const int k0   = wu * 192;
    float acc[NC];
#pragma unroll
    for (int i = 0; i < NC; ++i) acc[i] = 0.f;
#pragma unroll 8
    for (int kk = 0; kk < 192; ++kk) {
        const int k = k0 + kk;                       // uniform
        const float* ap = (k < 1024) ? (Axlo + (size_t)k * 64)
                                     : (Ahi + (size_t)(k - 1024) * 64);
        const float a = ap[lane];                    // coalesced 256B wave read
#pragma unroll
        for (int i = 0; i < NC; ++i)
            acc[i] = fmaf(a, WTc[(size_t)i * K1_ + k], acc[i]);  // W via scalar pipe
    }
#pragma unroll
    for (int i = 0; i < NC; ++i) part[(wu * 64 + lane) * NC + i] = acc[i];
    __syncthreads();
    float v = 0.f;
    if (tid < 64 * NC) {
        const int r = tid & 63, c = tid >> 6;
#pragma unroll
        for (int s = 0; s < 8; ++s) v += part[(s * 64 + r) * NC + c];
    }
    return v;
}

__global__ __launch_bounds__(512, 1) void revgru_main(
    const int* __restrict__ seq, const float* __restrict__ h0,
    const float* __restrict__ emb,
    const float* __restrict__ bzr1, const float* __restrict__ bg1,
    const float* __restrict__ bzr2, const float* __restrict__ bg2,
    float* __restrict__ ws, float* __restrict__ out)
{
    cg::grid_group grid = cg::this_grid();
    const int bi = blockIdx.x, tid = threadIdx.x;
    __shared__ float part[8 * 64 * 4];

    float* xT  = ws + OFF_XT;    // [k][row]
    float* hT  = ws + OFF_HT;    // [l][n][row]
    float* zT  = ws + OFF_ZT;    // [n<512][row]
    float* rhT = ws + OFF_RHT;   // [n<512][row]
    const float* WZR1 = ws + OFF_WZR1T;
    const float* WG1  = ws + OFF_WG1T;
    const float* WZR2 = ws + OFF_WZR2T;
    const float* WG2  = ws + OFF_WG2T;

    const int gtid = bi * 512 + tid, gstride = 256 * 512;
    // init hT = transpose(h0)
    for (int i = gtid; i < L_ * B_ * H_; i += gstride) {
        int l = i >> 16, rem = i & 65535, r = rem >> 10, n = rem & 1023;
        hT[((size_t)l * H_ + n) * 64 + r] = h0[i];
    }
    // gather xT for t=0
    for (int i = gtid; i < H_ * B_; i += gstride) {
        int k = i >> 6, r = i & 63;
        xT[i] = emb[(size_t)seq[r] * H_ + k];
    }
    grid.sync();

    for (int t = 0; t < T_; ++t) {
        for (int l = 0; l < L_; ++l) {
            const float* Axlo = (l == 0) ? xT : hT;  // layer-1 x = layer-0 h (transposed)

            // ---- P1: zr1 = [x, h2] @ Wzr1 ----
            {
                float v = phase_gemm<4>(Axlo, hT + ((size_t)l * H_ + Hh_) * 64,
                                        WZR1 + ((size_t)l * H_ + bi * 4) * K1_, part);
                if (tid < 256) {
                    int r = tid & 63, c = tid >> 6, cgl = bi * 4 + c;
                    v += bzr1[l * H_ + cgl];
                    float s = 1.f / (1.f + __expf(-v));
                    if (cgl < Hh_) zT[cgl * 64 + r] = s * MAXF + (1.f - MAXF);
                    else rhT[(cgl - Hh_) * 64 + r] =
                        s * hT[((size_t)l * H_ + cgl) * 64 + r];   // r1 * h2
                }
                // hidden: gather xT for t+1 (xT not used by any layer-1 phase)
                if (l == 1 && t + 1 < T_ && tid < 256) {
                    int r = tid & 63, kk = tid >> 6;
                    int k = bi * 4 + kk;
                    xT[k * 64 + r] = emb[(size_t)seq[(t + 1) * B_ + r] * H_ + k];
                }
                grid.sync();
            }
            // ---- P2: g1; h1 <- z1*h1 + (1-z1)*g1 ----
            {
                float v = phase_gemm<2>(Axlo, rhT,
                                        WG1 + ((size_t)l * Hh_ + bi * 2) * K1_, part);
                if (tid < 128) {
                    int r = tid & 63, c = tid >> 6, cgl = bi * 2 + c;
                    float g = tanhf(v + bg1[l * Hh_ + cgl]);
                    float z = zT[cgl * 64 + r];
                    size_t idx = ((size_t)l * H_ + cgl) * 64 + r;
                    hT[idx] = z * hT[idx] + (1.f - z) * g;
                }
                grid.sync();
            }
            // ---- P3: zr2 = [x, h1n] @ Wzr2 ----
            {
                float v = phase_gemm<4>(Axlo, hT + (size_t)l * H_ * 64,
                                        WZR2 + ((size_t)l * H_ + bi * 4) * K1_, part);
                if (tid < 256) {
                    int r = tid & 63, c = tid >> 6, cgl = bi * 4 + c;
                    v += bzr2[l * H_ + cgl];
                    float s = 1.f / (1.f + __expf(-v));
                    if (cgl < Hh_) zT[cgl * 64 + r] = s * MAXF + (1.f - MAXF);
                    else rhT[(cgl - Hh_) * 64 + r] =
                        s * hT[((size_t)l * H_ + (cgl - Hh_)) * 64 + r];  // r2 * h1n
                }
                grid.sync();
            }
            // ---- P4: g2; h2 <- z2*h2 + (1-z2)*g2 ----
            {
                float v = phase_gemm<2>(Axlo, rhT,
                                        WG2 + ((size_t)l * Hh_ + bi * 2) * K1_, part);
                if (tid < 128) {
                    int r = tid & 63, c = tid >> 6, cgl = bi * 2 + c;
                    float g = tanhf(v + bg2[l * Hh_ + cgl]);
                    float z = zT[cgl * 64 + r];
                    size_t idx = ((size_t)l * H_ + Hh_ + cgl) * 64 + r;
                    hT[idx] = z * hT[idx] + (1.f - z) * g;
                }
                grid.sync();
            }
        }
    }
    // out[l][r][n] = hT[l][n][r]
    for (int i = gtid; i < L_ * B_ * H_; i += gstride) {
        int l = i >> 16, rem = i & 65535, r = rem >> 10, n = rem & 1023;
        out[i] = hT[((size_t)l * H_ + n) * 64 + r];
    }
}

extern "C" void kernel_launch(void* const* d_in, const int* in_sizes, int n_in,
                              void* d_out, int out_size, void* d_ws, size_t ws_size,
                              hipStream_t stream) {
    (void)in_sizes; (void)n_in; (void)out_size; (void)ws_size;
    const int*   seq  = (const int*)  d_in[0];
    const float* h0   = (const float*)d_in[1];
    const float* emb  = (const float*)d_in[2];
    const float* Wzr1 = (const float*)d_in[3];
    const float* bzr1 = (const float*)d_in[4];
    const float* Wg1  = (const float*)d_in[5];
    const float* bg1  = (const float*)d_in[6];
    const float* Wzr2 = (const float*)d_in[7];
    const float* bzr2 = (const float*)d_in[8];
    const float* Wg2  = (const float*)d_in[9];
    const float* bg2  = (const float*)d_in[10];
    float* out = (float*)d_out;
    float* ws  = (float*)d_ws;

    transpose_w<<<dim3(24, 16, 2), 256, 0, stream>>>(Wzr1, ws + OFF_WZR1T, H_);
    transpose_w<<<dim3(24,  8, 2), 256, 0, stream>>>(Wg1,  ws + OFF_WG1T,  Hh_);
    transpose_w<<<dim3(24, 16, 2), 256, 0, stream>>>(Wzr2, ws + OFF_WZR2T, H_);
    transpose_w<<<dim3(24,  8, 2), 256, 0, stream>>>(Wg2,  ws + OFF_WG2T,  Hh_);

    void* args[] = { &seq, &h0, &emb, &bzr1, &bg1, &bzr2, &bg2, &ws, &out };
    hipLaunchCooperativeKernel((void*)revgru_main, dim3(256), dim3(512), args, 0, stream);
}